// Round 1
// baseline (228.641 us; speedup 1.0000x reference)
//
#include <hip/hip_runtime.h>
#include <math.h>

#define BATCH 8
#define NPRI  4096
#define TOPK  200

typedef unsigned long long u64;
typedef unsigned int u32;

#define WS_SOA (BATCH * NPRI)  // floats per SoA array

// correctly-rounded f32 exp via f64
__device__ __forceinline__ float exp_f32_cr(float x) { return (float)exp((double)x); }

// ---------------------------------------------------------------------------
// K1: scores + stable-descending sort keys + bitonic sort + box decode -> SoA
// ---------------------------------------------------------------------------
__global__ __launch_bounds__(1024) void sort_decode_kernel(
    const float* __restrict__ loc, const float* __restrict__ conf,
    const float* __restrict__ prior, float* __restrict__ ws) {
  __shared__ u64 sk[NPRI];
  const int b = blockIdx.x, t = threadIdx.x;

  for (int i = t; i < NPRI; i += 1024) {
    float c0 = conf[(b * NPRI + i) * 2 + 0];
    float c1 = conf[(b * NPRI + i) * 2 + 1];
    float m  = fmaxf(c0, c1);
    float e0 = exp_f32_cr(__fsub_rn(c0, m));
    float e1 = exp_f32_cr(__fsub_rn(c1, m));
    float s  = __fdiv_rn(e1, __fadd_rn(e0, e1));
    // descending score, ties -> ascending original index (stable argsort(-s))
    sk[i] = ((u64)(~__float_as_uint(s)) << 32) | (u32)i;
  }
  __syncthreads();

  // bitonic sort ascending (u64 keys), N=4096, T=1024
  for (int k = 2; k <= NPRI; k <<= 1) {
    for (int j = k >> 1; j > 0; j >>= 1) {
      for (int i = t; i < NPRI; i += 1024) {
        int ixj = i ^ j;
        if (ixj > i) {
          u64 a = sk[i], c = sk[ixj];
          bool up = ((i & k) == 0);
          if ((a > c) == up) { sk[i] = c; sk[ixj] = a; }
        }
      }
      __syncthreads();
    }
  }

  float* sx1 = ws;
  float* sy1 = ws + 1 * WS_SOA;
  float* sx2 = ws + 2 * WS_SOA;
  float* sy2 = ws + 3 * WS_SOA;
  float* sar = ws + 4 * WS_SOA;
  float* ssc = ws + 5 * WS_SOA;

  for (int r = t; r < NPRI; r += 1024) {
    u64 key = sk[r];
    int i   = (int)(u32)key;
    float s = __uint_as_float(~(u32)(key >> 32));
    float4 l = ((const float4*)loc)[b * NPRI + i];
    float4 p = ((const float4*)prior)[i];
    // cx = p0 + (l0*0.1)*p2 ; w = p2 * exp(l2*0.2) — exact f32 op order
    float cx = __fadd_rn(p.x, __fmul_rn(__fmul_rn(l.x, 0.1f), p.z));
    float cy = __fadd_rn(p.y, __fmul_rn(__fmul_rn(l.y, 0.1f), p.w));
    float w  = __fmul_rn(p.z, exp_f32_cr(__fmul_rn(l.z, 0.2f)));
    float h  = __fmul_rn(p.w, exp_f32_cr(__fmul_rn(l.w, 0.2f)));
    float hw = __fmul_rn(w, 0.5f), hh = __fmul_rn(h, 0.5f);
    float x1 = __fsub_rn(cx, hw), x2 = __fadd_rn(cx, hw);
    float y1 = __fsub_rn(cy, hh), y2 = __fadd_rn(cy, hh);
    int o = b * NPRI + r;
    sx1[o] = x1; sy1[o] = y1; sx2[o] = x2; sy2[o] = y2;
    sar[o] = __fmul_rn(__fsub_rn(x2, x1), __fsub_rn(y2, y1));
    ssc[o] = s;
  }
}

// ---------------------------------------------------------------------------
// K2: suppression bitmask, words w >= rowgroup only (upper triangle)
// grid: x = 64 rowgroups * 4 wordgroups, y = image. block = 256 (4 waves).
// ---------------------------------------------------------------------------
__global__ __launch_bounds__(256) void mask_kernel(const float* __restrict__ ws,
                                                   u64* __restrict__ mask) {
  const int a = blockIdx.x >> 2, wg = blockIdx.x & 3, b = blockIdx.y;
  if (16 * wg + 15 < a) return;  // entire word range below diagonal

  __shared__ float jx1[1024], jy1[1024], jx2[1024], jy2[1024], jar[1024];
  const float* sx1 = ws;
  const float* sy1 = ws + 1 * WS_SOA;
  const float* sx2 = ws + 2 * WS_SOA;
  const float* sy2 = ws + 3 * WS_SOA;
  const float* sar = ws + 4 * WS_SOA;

  const int t = threadIdx.x, jbase = wg * 1024;
  for (int v = t; v < 1024; v += 256) {
    int o = b * NPRI + jbase + v;
    jx1[v] = sx1[o]; jy1[v] = sy1[o]; jx2[v] = sx2[o]; jy2[v] = sy2[o]; jar[v] = sar[o];
  }
  __syncthreads();

  const int lane = t & 63, wv = t >> 6;
  const int i = a * 64 + lane;
  const int o = b * NPRI + i;
  const float ix1 = sx1[o], iy1 = sy1[o], ix2 = sx2[o], iy2 = sy2[o], iar = sar[o];
  // exact threshold: fl(inter/uni) > 0.45f  <=>  inter > M*uni (exact in f64)
  const double M = 0.5 * ((double)0.45f + (double)__uint_as_float(0x3EE66667u));

  const int w0 = 16 * wg + 4 * wv;
  for (int w = w0; w < w0 + 4; ++w) {
    if (w < a) continue;  // below diagonal: not stored, never read meaningfully
    u64 bits = 0;
    const int jl = w * 64 - jbase;
#pragma unroll 8
    for (int jj = 0; jj < 64; ++jj) {
      float bx1 = jx1[jl + jj], by1 = jy1[jl + jj];
      float bx2 = jx2[jl + jj], by2 = jy2[jl + jj], bar = jar[jl + jj];
      float iw = fmaxf(__fsub_rn(fminf(ix2, bx2), fmaxf(ix1, bx1)), 0.0f);
      float ih = fmaxf(__fsub_rn(fminf(iy2, by2), fmaxf(iy1, by1)), 0.0f);
      float inter = __fmul_rn(iw, ih);
      float uni   = __fsub_rn(__fadd_rn(iar, bar), inter);
      if ((double)inter > M * (double)uni) bits |= (1ull << jj);
    }
    mask[(((u32)(b * NPRI + i)) << 6) | (u32)w] = bits;
  }
}

// ---------------------------------------------------------------------------
// K3: sequential greedy scan, 1 wave per image. removed mask distributed
// 1 u64/lane; 64 chunks; diagonal block via branchless shfl-fed serial loop;
// kept rows applied wave-parallel from LDS. Early-exit at TOPK kept.
// ---------------------------------------------------------------------------
__global__ __launch_bounds__(64) void scan_kernel(const float* __restrict__ ws,
                                                  const u64* __restrict__ mask,
                                                  float* __restrict__ out) {
  __shared__ u64 cm[64][66];  // 66: 16B-aligned row stride, breaks diag-read conflict
  __shared__ int klist[TOPK];
  const int b = blockIdx.x, lane = threadIdx.x;

  const float* sx1 = ws;
  const float* sy1 = ws + 1 * WS_SOA;
  const float* sx2 = ws + 2 * WS_SOA;
  const float* sy2 = ws + 3 * WS_SOA;
  const float* ssc = ws + 5 * WS_SOA;
  const u64* mb = mask + (((u64)b * NPRI) << 6);

  u64 removed = 0;
  int cnt = 0;

  for (int w = 0; w < 64; ++w) {
    __syncthreads();
#pragma unroll 8
    for (int r = 0; r < 64; ++r)
      cm[r][lane] = mb[(((u32)(w * 64 + r)) << 6) | (u32)lane];
    __syncthreads();

    float sc = ssc[b * NPRI + w * 64 + lane];
    u64 vm = __ballot(sc > 0.01f);
    if (vm == 0) break;  // scores sorted desc: nothing valid from here on

    u64 Dreg = cm[lane][w];          // this lane's row: diagonal word
    u64 rw   = __shfl(removed, w);   // removed word for this chunk (replicated)
    u64 ck   = 0;

    for (int g = 0; g < 64; g += 8) {
      u64 d[8];
#pragma unroll
      for (int q = 0; q < 8; ++q) d[q] = __shfl(Dreg, g + q);
#pragma unroll
      for (int q = 0; q < 8; ++q) {
        u64 kbit = ((vm & ~rw) >> (g + q)) & 1ull;
        rw |= d[q] & (0ull - kbit);
        ck |= kbit << (g + q);
      }
    }

    // apply kept rows' full mask rows to distributed removed
    u64 kk = ck;
    while (kk) {
      int bb = __ffsll((unsigned long long)kk) - 1;
      kk &= kk - 1;
      removed |= cm[bb][lane];
    }

    // record kept indices
    if ((ck >> lane) & 1ull) {
      int pos = cnt + __popcll(ck & ((1ull << lane) - 1ull));
      if (pos < TOPK) klist[pos] = w * 64 + lane;
    }
    cnt += __popcll(ck);
    if (cnt >= TOPK) break;
  }
  __syncthreads();

  int total = cnt < TOPK ? cnt : TOPK;
  for (int p = lane; p < total; p += 64) {
    int i = klist[p];
    int o = b * NPRI + i;
    float* dst = out + (((size_t)b * 2 + 1) * TOPK + p) * 5;
    dst[0] = ssc[o]; dst[1] = sx1[o]; dst[2] = sy1[o]; dst[3] = sx2[o]; dst[4] = sy2[o];
  }
}

// ---------------------------------------------------------------------------
extern "C" void kernel_launch(void* const* d_in, const int* in_sizes, int n_in,
                              void* d_out, int out_size, void* d_ws, size_t ws_size,
                              hipStream_t stream) {
  const float* loc   = (const float*)d_in[0];
  const float* conf  = (const float*)d_in[1];
  const float* prior = (const float*)d_in[2];
  float* out = (float*)d_out;
  float* ws  = (float*)d_ws;
  u64*   msk = (u64*)((char*)d_ws + (size_t)6 * WS_SOA * sizeof(float));

  hipMemsetAsync(d_out, 0, (size_t)out_size * sizeof(float), stream);
  sort_decode_kernel<<<BATCH, 1024, 0, stream>>>(loc, conf, prior, ws);
  mask_kernel<<<dim3(256, BATCH), 256, 0, stream>>>(ws, msk);
  scan_kernel<<<BATCH, 64, 0, stream>>>(ws, msk, out);
}

// Round 2
// 167.567 us; speedup vs baseline: 1.3645x; 1.3645x over previous
//
#include <hip/hip_runtime.h>
#include <math.h>

#define BATCH 8
#define NPRI  4096
#define TOPK  200

typedef unsigned long long u64;
typedef unsigned int u32;

#define WS_SOA (BATCH * NPRI)  // floats per SoA array

// correctly-rounded f32 exp via f64 (matches numpy float32 exp bit-exactly)
__device__ __forceinline__ float exp_f32_cr(float x) { return (float)exp((double)x); }

__device__ __forceinline__ u64 shflx64(u64 v, int m) {
  u32 lo = (u32)__shfl_xor((int)(u32)v, m);
  u32 hi = (u32)__shfl_xor((int)(u32)(v >> 32), m);
  return ((u64)hi << 32) | lo;
}

__device__ __forceinline__ void cmpex(u64& x, u64& y, bool up) {
  // up: x should end <= y
  if ((x > y) == up) { u64 t = x; x = y; y = t; }
}

// ---------------------------------------------------------------------------
// K1: scores + stable sort (register/shfl/LDS hybrid bitonic) + decode -> SoA
// 8 blocks x 1024. Each thread holds 4 consecutive elements p0..p0+3.
// j<=2 register, j=4..128 shfl_xor (wave-local 256-seg), j>=256 LDS (14 barriers).
// ---------------------------------------------------------------------------
__global__ __launch_bounds__(1024) void sort_decode_kernel(
    const float* __restrict__ loc, const float* __restrict__ conf,
    const float* __restrict__ prior, float* __restrict__ ws) {
  __shared__ u64 sk[NPRI];  // 32 KB
  const int b = blockIdx.x, t = threadIdx.x;
  const int lane = t & 63;
  const int p0 = t << 2;  // this thread's 4 consecutive positions

  // ---- build keys: descending score, ties ascending index ----
  u64 r0, r1, r2, r3;
  {
    const float4* cf4 = (const float4*)conf;
    int base = (b * NPRI + p0) >> 1;  // float4 index (2 boxes per float4)
    float4 cA = cf4[base], cB = cf4[base + 1];
    float c0[4] = {cA.x, cA.z, cB.x, cB.z};
    float c1[4] = {cA.y, cA.w, cB.y, cB.w};
    u64 rr[4];
#pragma unroll
    for (int q = 0; q < 4; ++q) {
      float m = fmaxf(c0[q], c1[q]);
      float e0 = exp_f32_cr(__fsub_rn(c0[q], m));
      float e1 = exp_f32_cr(__fsub_rn(c1[q], m));
      float s = __fdiv_rn(e1, __fadd_rn(e0, e1));
      rr[q] = ((u64)(~__float_as_uint(s)) << 32) | (u32)(p0 + q);
    }
    r0 = rr[0]; r1 = rr[1]; r2 = rr[2]; r3 = rr[3];
  }

  // ---- bitonic sort ascending on u64 keys ----
  for (int k = 2; k <= NPRI; k <<= 1) {
    if (k >= 512) {
      // cross-wave strides via LDS
      sk[p0 + 0] = r0; sk[p0 + 1] = r1; sk[p0 + 2] = r2; sk[p0 + 3] = r3;
      __syncthreads();
      for (int j = k >> 1; j >= 256; j >>= 1) {
#pragma unroll
        for (int e = 0; e < 4; ++e) {
          int i = t + (e << 10);
          int ixj = i ^ j;
          if (ixj > i) {
            u64 A = sk[i], B = sk[ixj];
            bool up = ((i & k) == 0);
            if ((A > B) == up) { sk[i] = B; sk[ixj] = A; }
          }
        }
        __syncthreads();
      }
      r0 = sk[p0 + 0]; r1 = sk[p0 + 1]; r2 = sk[p0 + 2]; r3 = sk[p0 + 3];
    }
    // wave-local strides j = min(k/2,128) .. 4 via shfl_xor
    {
      bool up = ((p0 & k) == 0);  // k>=8 in this loop -> uniform over q
      for (int j = ((k >> 1) > 128 ? 128 : (k >> 1)); j >= 4; j >>= 1) {
        int m = j >> 2;
        bool lower = ((lane & m) == 0);
        bool takeMin = (lower == up);
        u64 o0 = shflx64(r0, m), o1 = shflx64(r1, m);
        u64 o2 = shflx64(r2, m), o3 = shflx64(r3, m);
        r0 = takeMin ? (r0 < o0 ? r0 : o0) : (r0 > o0 ? r0 : o0);
        r1 = takeMin ? (r1 < o1 ? r1 : o1) : (r1 > o1 ? r1 : o1);
        r2 = takeMin ? (r2 < o2 ? r2 : o2) : (r2 > o2 ? r2 : o2);
        r3 = takeMin ? (r3 < o3 ? r3 : o3) : (r3 > o3 ? r3 : o3);
      }
    }
    // j = 2 (register)
    if (k >= 4) {
      bool up = ((p0 & k) == 0);
      cmpex(r0, r2, up); cmpex(r1, r3, up);
    }
    // j = 1 (register)
    if (k == 2) {
      cmpex(r0, r1, true); cmpex(r2, r3, false);
    } else {
      bool up = ((p0 & k) == 0);
      cmpex(r0, r1, up); cmpex(r2, r3, up);
    }
  }

  // ---- decode: rank p0+q holds key r[q] ----
  float* sx1 = ws;
  float* sy1 = ws + 1 * WS_SOA;
  float* sx2 = ws + 2 * WS_SOA;
  float* sy2 = ws + 3 * WS_SOA;
  float* sar = ws + 4 * WS_SOA;
  float* ssc = ws + 5 * WS_SOA;

  u64 keys[4] = {r0, r1, r2, r3};
#pragma unroll
  for (int q = 0; q < 4; ++q) {
    u64 key = keys[q];
    int i = (int)(u32)key;
    float s = __uint_as_float(~(u32)(key >> 32));
    float4 l = ((const float4*)loc)[b * NPRI + i];
    float4 p = ((const float4*)prior)[i];
    float cx = __fadd_rn(p.x, __fmul_rn(__fmul_rn(l.x, 0.1f), p.z));
    float cy = __fadd_rn(p.y, __fmul_rn(__fmul_rn(l.y, 0.1f), p.w));
    float w  = __fmul_rn(p.z, exp_f32_cr(__fmul_rn(l.z, 0.2f)));
    float h  = __fmul_rn(p.w, exp_f32_cr(__fmul_rn(l.w, 0.2f)));
    float hw = __fmul_rn(w, 0.5f), hh = __fmul_rn(h, 0.5f);
    float x1 = __fsub_rn(cx, hw), x2 = __fadd_rn(cx, hw);
    float y1 = __fsub_rn(cy, hh), y2 = __fadd_rn(cy, hh);
    int o = b * NPRI + p0 + q;
    sx1[o] = x1; sy1[o] = y1; sx2[o] = x2; sy2[o] = y2;
    sar[o] = __fmul_rn(__fsub_rn(x2, x1), __fsub_rn(y2, y1));
    ssc[o] = s;
  }
}

// ---------------------------------------------------------------------------
// K2: suppression bitmask, flat-balanced upper-triangle word-tasks.
// 2080 tasks/img = 520 waves x 4 tasks. 130 blocks/img x 256 thr (4 waves).
// Mask layout TRANSPOSED: mask[((b*64 + wcol) << 12) + row]  -> coalesced store.
// ---------------------------------------------------------------------------
#define MBLK_PER_IMG 130
__global__ __launch_bounds__(256) void mask_kernel(const float* __restrict__ ws,
                                                   u64* __restrict__ mask) {
  __shared__ float4 jbox[4][64];
  __shared__ float jarea[4][64];
  const int blk = blockIdx.x;
  const int b = blk / MBLK_PER_IMG, wb = blk % MBLK_PER_IMG;
  const int t = threadIdx.x, lane = t & 63, wv = t >> 6;
  const int waveid = wb * 4 + wv;  // 0..519

  // decode first task id -> (a, w) in row-major triangle enumeration
  int a = 0, rem = waveid * 4;
  while (rem >= 64 - a) { rem -= 64 - a; ++a; }
  int w = a + rem;

  const float* sx1 = ws;
  const float* sy1 = ws + 1 * WS_SOA;
  const float* sx2 = ws + 2 * WS_SOA;
  const float* sy2 = ws + 3 * WS_SOA;
  const float* sar = ws + 4 * WS_SOA;
  // exact threshold: fl(inter/uni) > 0.45f  <=>  inter > M*uni (exact in f64)
  const double M = 0.5 * ((double)0.45f + (double)__uint_as_float(0x3EE66667u));

#pragma unroll 1
  for (int s = 0; s < 4; ++s) {
    const int i = a * 64 + lane, o = b * NPRI + i;
    const float ix1 = sx1[o], iy1 = sy1[o], ix2 = sx2[o], iy2 = sy2[o], iar = sar[o];

    const int jo = b * NPRI + w * 64 + lane;
    jbox[wv][lane] = make_float4(sx1[jo], sy1[jo], sx2[jo], sy2[jo]);
    jarea[wv][lane] = sar[jo];
    __builtin_amdgcn_wave_barrier();  // keep LDS write before reads (same wave: DS in-order)

    u64 bits = 0;
#pragma unroll 8
    for (int jj = 0; jj < 64; ++jj) {
      float4 jb = jbox[wv][jj];
      float bar = jarea[wv][jj];
      float iw = fmaxf(__fsub_rn(fminf(ix2, jb.z), fmaxf(ix1, jb.x)), 0.0f);
      float ih = fmaxf(__fsub_rn(fminf(iy2, jb.w), fmaxf(iy1, jb.y)), 0.0f);
      float inter = __fmul_rn(iw, ih);
      float uni   = __fsub_rn(__fadd_rn(iar, bar), inter);
      if ((double)inter > M * (double)uni) bits |= (1ull << jj);
    }
    mask[(((u64)(b * 64 + w)) << 12) + (u32)i] = bits;

    if (++w == 64) { ++a; w = a; }
    __builtin_amdgcn_wave_barrier();
  }
}

// ---------------------------------------------------------------------------
// K3: greedy scan, 1 block (4 waves) per image. Wave 0 resolves chunk w while
// waves 1-3 prefetch chunk w+1 into the other LDS buffer. Early-exit at TOPK.
// ---------------------------------------------------------------------------
__global__ __launch_bounds__(256) void scan_kernel(const float* __restrict__ ws,
                                                   const u64* __restrict__ mask,
                                                   float* __restrict__ out) {
  __shared__ u64 cm[2][64][66];  // double-buffered 64x64 tile (+pad)
  __shared__ int klist[TOPK];
  __shared__ int sstop, stotal;
  const int b = blockIdx.x;
  const int t = threadIdx.x, lane = t & 63, wv = t >> 6;

  const float* sx1 = ws;
  const float* sy1 = ws + 1 * WS_SOA;
  const float* sx2 = ws + 2 * WS_SOA;
  const float* sy2 = ws + 3 * WS_SOA;
  const float* ssc = ws + 5 * WS_SOA;
  const u64* colbase = mask + (((u64)(b * 64 + lane)) << 12);  // this lane's column

  // preload chunk 0 (all 4 waves)
  for (int r = wv * 16; r < wv * 16 + 16; ++r) cm[0][r][lane] = colbase[r];
  if (t == 0) { sstop = 0; stotal = 0; }
  __syncthreads();

  u64 removed = 0;  // wave 0, distributed 1 word/lane
  int cnt = 0;

  for (int w = 0; w < 64; ++w) {
    if (wv > 0) {
      if (w + 1 < 64) {
        const u64* cb = colbase + (w + 1) * 64;
        for (int r = wv - 1; r < 64; r += 3) cm[(w + 1) & 1][r][lane] = cb[r];
      }
    } else {
      const int buf = w & 1;
      float sc = ssc[b * NPRI + w * 64 + lane];
      u64 vm = __ballot(sc > 0.01f);
      bool stop = false;
      if (vm == 0) {
        stop = true;  // sorted desc: nothing valid from here on
      } else {
        u64 Dreg = cm[buf][lane][w];        // lane's row diagonal word
        u64 rw = shflx64(removed, 0);       // placeholder (overwritten below)
        rw = __shfl(removed, w);            // removed word for this chunk
        u64 ck = 0;
        for (int g = 0; g < 64; g += 8) {
          u64 d[8];
#pragma unroll
          for (int q = 0; q < 8; ++q) d[q] = __shfl(Dreg, g + q);
#pragma unroll
          for (int q = 0; q < 8; ++q) {
            u64 kbit = ((vm & ~rw) >> (g + q)) & 1ull;
            rw |= d[q] & (0ull - kbit);
            ck |= kbit << (g + q);
          }
        }
        // apply kept rows' full mask rows to distributed removed
        u64 kk = ck;
        while (kk) {
          int bb = __ffsll((unsigned long long)kk) - 1;
          kk &= kk - 1;
          removed |= cm[buf][bb][lane];
        }
        if ((ck >> lane) & 1ull) {
          int pos = cnt + __popcll(ck & ((1ull << lane) - 1ull));
          if (pos < TOPK) klist[pos] = w * 64 + lane;
        }
        cnt += __popcll(ck);
        if (cnt >= TOPK) stop = true;
      }
      if (lane == 0) { sstop = stop ? 1 : 0; stotal = cnt < TOPK ? cnt : TOPK; }
    }
    __syncthreads();
    if (sstop) break;
  }

  int total = stotal;
  for (int p = t; p < total; p += 256) {
    int i = klist[p];
    int o = b * NPRI + i;
    float* dst = out + (((size_t)b * 2 + 1) * TOPK + p) * 5;
    dst[0] = ssc[o]; dst[1] = sx1[o]; dst[2] = sy1[o]; dst[3] = sx2[o]; dst[4] = sy2[o];
  }
}

// ---------------------------------------------------------------------------
extern "C" void kernel_launch(void* const* d_in, const int* in_sizes, int n_in,
                              void* d_out, int out_size, void* d_ws, size_t ws_size,
                              hipStream_t stream) {
  const float* loc   = (const float*)d_in[0];
  const float* conf  = (const float*)d_in[1];
  const float* prior = (const float*)d_in[2];
  float* out = (float*)d_out;
  float* ws  = (float*)d_ws;
  u64*   msk = (u64*)((char*)d_ws + (size_t)6 * WS_SOA * sizeof(float));

  hipMemsetAsync(d_out, 0, (size_t)out_size * sizeof(float), stream);
  sort_decode_kernel<<<BATCH, 1024, 0, stream>>>(loc, conf, prior, ws);
  mask_kernel<<<MBLK_PER_IMG * BATCH, 256, 0, stream>>>(ws, msk);
  scan_kernel<<<BATCH, 256, 0, stream>>>(ws, msk, out);
}